// Round 4
// baseline (104.872 us; speedup 1.0000x reference)
//
#include <hip/hip_runtime.h>
#include <math.h>

#define Bv 2
#define Dv 192
#define Hv 192
#define Wv 192
#define Nv (Dv*Hv*Wv)          // 7,077,888 voxels per batch
#define NOUT (Bv*Nv)           // 14,155,776 warped elements

// Output tile per block: 8 (x) * 8 (y) * 8 (z) = 512 threads, one voxel each.
#define TX 8
#define TY 8
#define TZ 8
#define LDSF 12288             // 48 KB source-bbox stage

__device__ __forceinline__ void mm3(const float a[3][3], const float b[3][3], float c[3][3]) {
#pragma unroll
    for (int i = 0; i < 3; ++i)
#pragma unroll
        for (int j = 0; j < 3; ++j)
            c[i][j] = a[i][0]*b[0][j] + a[i][1]*b[1][j] + a[i][2]*b[2][j];
}

__global__ void compose_mats_kernel(const float* __restrict__ affine,
                                    const float* __restrict__ scale,
                                    const float* __restrict__ translate,
                                    const float* __restrict__ shear,
                                    float* __restrict__ mats_out) {
    int b = threadIdx.x;
    if (b >= Bv) return;

    float ax = affine[b*3+0], ay = affine[b*3+1], az = affine[b*3+2];
    float cx = cosf(ax), sx = sinf(ax);
    float cy = cosf(ay), sy = sinf(ay);
    float cz = cosf(az), sz = sinf(az);

    // _mk_mat transposes the written rows -> these are the transposed matrices.
    float rx[3][3] = {{1.f,0.f,0.f},{0.f,cx,sx},{0.f,-sx,cx}};
    float ry[3][3] = {{cy,0.f,-sy},{0.f,1.f,0.f},{sy,0.f,cy}};
    float rz[3][3] = {{cz,sz,0.f},{-sz,cz,0.f},{0.f,0.f,1.f}};

    float t0 = tanf(shear[b*6+0]), t1 = tanf(shear[b*6+1]), t2 = tanf(shear[b*6+2]);
    float t3 = tanf(shear[b*6+3]), t4 = tanf(shear[b*6+4]), t5 = tanf(shear[b*6+5]);
    float sh[3][3] = {{1.f,t2,t4},{t0,1.f,t5},{t1,t3,1.f}};

    float s0 = scale[b*3+0], s1 = scale[b*3+1], s2 = scale[b*3+2];

    float m1[3][3], m2[3][3], m3s[3][3], mat3[3][3];
    mm3(ry, rx, m1);
    mm3(rz, m1, m2);
#pragma unroll
    for (int j = 0; j < 3; ++j) { m3s[0][j] = s0*m2[0][j]; m3s[1][j] = s1*m2[1][j]; m3s[2][j] = s2*m2[2][j]; }
    mm3(sh, m3s, mat3);

    float tr0 = translate[b*3+0], tr1 = translate[b*3+1], tr2 = translate[b*3+2];

    float a00 = mat3[0][0], a01 = mat3[0][1], a02 = mat3[0][2];
    float a10 = mat3[1][0], a11 = mat3[1][1], a12 = mat3[1][2];
    float a20 = mat3[2][0], a21 = mat3[2][1], a22 = mat3[2][2];
    float c00 =  (a11*a22 - a12*a21);
    float c01 = -(a10*a22 - a12*a20);
    float c02 =  (a10*a21 - a11*a20);
    float det = a00*c00 + a01*c01 + a02*c02;
    float rdet = 1.0f / det;
    float inv3[3][3];
    inv3[0][0] = c00*rdet;
    inv3[0][1] = (a02*a21 - a01*a22)*rdet;
    inv3[0][2] = (a01*a12 - a02*a11)*rdet;
    inv3[1][0] = c01*rdet;
    inv3[1][1] = (a00*a22 - a02*a20)*rdet;
    inv3[1][2] = (a02*a10 - a00*a12)*rdet;
    inv3[2][0] = c02*rdet;
    inv3[2][1] = (a01*a20 - a00*a21)*rdet;
    inv3[2][2] = (a00*a11 - a01*a10)*rdet;

    float* mo = mats_out + b*12;
#pragma unroll
    for (int i = 0; i < 3; ++i) {
        mo[i*4+0] = mat3[i][0]; mo[i*4+1] = mat3[i][1]; mo[i*4+2] = mat3[i][2];
    }
    mo[0*4+3] = tr0; mo[1*4+3] = tr1; mo[2*4+3] = tr2;

    float* io = mats_out + 24 + b*12;
#pragma unroll
    for (int i = 0; i < 3; ++i) {
        io[i*4+0] = inv3[i][0]; io[i*4+1] = inv3[i][1]; io[i*4+2] = inv3[i][2];
        io[i*4+3] = -(inv3[i][0]*tr0 + inv3[i][1]*tr1 + inv3[i][2]*tr2);
    }
}

__global__ __launch_bounds__(512) void warp_kernel(const float* __restrict__ src,
                                                   const float* __restrict__ mats,
                                                   float* __restrict__ out) {
    __shared__ float lds[LDSF];

    int t  = threadIdx.x;
    int lx = t & (TX-1);
    int ly = (t >> 3) & (TY-1);
    int lz = t >> 6;

    int W0 = blockIdx.x * TX;
    int H0 = blockIdx.y * TY;
    int zt = blockIdx.z;                 // 0 .. (Dv/TZ)*Bv - 1
    int b  = zt / (Dv/TZ);               // uniform
    int Z0 = (zt % (Dv/TZ)) * TZ;

    int w = W0 + lx, h = H0 + ly, z = Z0 + lz;

    const float* M = mats + b*12;        // uniform -> scalar loads
    float m00 = M[0], m01 = M[1],  m02 = M[2],  m03 = M[3];
    float m10 = M[4], m11 = M[5],  m12 = M[6],  m13 = M[7];
    float m20 = M[8], m21 = M[9],  m22 = M[10], m23 = M[11];

    // ix = m00*(w+.5) + m01*(h+.5) + m02*(z+.5) + Cx
    float Cx = 96.0f*(m03 - m00 - m01 - m02) + 95.5f;
    float Cy = 96.0f*(m13 - m10 - m11 - m12) + 95.5f;
    float Cz = 96.0f*(m23 - m20 - m21 - m22) + 95.5f;

    float fw = w + 0.5f, fh = h + 0.5f, fzc = z + 0.5f;
    float ix = fmaf(m00, fw, fmaf(m01, fh, fmaf(m02, fzc, Cx)));
    float iy = fmaf(m10, fw, fmaf(m11, fh, fmaf(m12, fzc, Cy)));
    float iz = fmaf(m20, fw, fmaf(m21, fh, fmaf(m22, fzc, Cz)));

    float flx = floorf(ix), fly = floorf(iy), flz = floorf(iz);
    float wx = ix - flx, wy = iy - fly, wz = iz - flz;
    int x0 = (int)flx, y0 = (int)fly, z0 = (int)flz;

    const float* sb = src + (size_t)b * Nv;

    // ---- block-uniform source bbox (center +/- half-extent of tile corners) ----
    float wc = W0 + 4.0f, hc = H0 + 4.0f, zcc = Z0 + 4.0f;
    float cxv = fmaf(m00, wc, fmaf(m01, hc, fmaf(m02, zcc, Cx)));
    float cyv = fmaf(m10, wc, fmaf(m11, hc, fmaf(m12, zcc, Cy)));
    float czv = fmaf(m20, wc, fmaf(m21, hc, fmaf(m22, zcc, Cz)));
    float hxv = 3.5f*(fabsf(m00) + fabsf(m01) + fabsf(m02));
    float hyv = 3.5f*(fabsf(m10) + fabsf(m11) + fabsf(m12));
    float hzv = 3.5f*(fabsf(m20) + fabsf(m21) + fabsf(m22));

    int bx0 = (int)floorf(cxv - hxv) - 1, bx1 = (int)floorf(cxv + hxv) + 2;
    int by0 = (int)floorf(cyv - hyv) - 1, by1 = (int)floorf(cyv + hyv) + 2;
    int bz0 = (int)floorf(czv - hzv) - 1, bz1 = (int)floorf(czv + hzv) + 2;

    int ex = (bx1 - bx0 + 1) | 1;        // odd stride -> no row bank conflicts
    int ey = by1 - by0 + 1;
    int ez = bz1 - bz0 + 1;
    int exReal = bx1 - bx0 + 1;
    int vol = ex * ey * ez;

    float acc = 0.0f;

    if (vol <= LDSF) {
        // ---- stage bbox into LDS (zero-filled outside the volume) ----
        for (int dz = lz; dz < ez; dz += TZ) {
            int gz = bz0 + dz;
            int zrow = dz * ey;
            for (int dy = ly; dy < ey; dy += TY) {
                int gy = by0 + dy;
                int rowbase = (zrow + dy) * ex;
                int gbase = (gz * Hv + gy) * Wv;
                bool rowok = ((unsigned)gy < (unsigned)Hv) & ((unsigned)gz < (unsigned)Dv);
                for (int dx = lx; dx < exReal; dx += TX) {
                    int gx = bx0 + dx;
                    bool v = rowok & ((unsigned)gx < (unsigned)Wv);
                    float val = v ? sb[gbase + gx] : 0.0f;
                    lds[rowbase + dx] = val;
                }
            }
        }
        __syncthreads();

        int lix = x0 - bx0, liy = y0 - by0, liz = z0 - bz0;
        int base  = (liz * ey + liy) * ex + lix;
        int base1 = base + ey * ex;
        float v000 = lds[base],         v001 = lds[base + 1];
        float v010 = lds[base + ex],    v011 = lds[base + ex + 1];
        float v100 = lds[base1],        v101 = lds[base1 + 1];
        float v110 = lds[base1 + ex],   v111 = lds[base1 + ex + 1];

        float c00 = fmaf(wx, v001 - v000, v000);
        float c01 = fmaf(wx, v011 - v010, v010);
        float c10 = fmaf(wx, v101 - v100, v100);
        float c11 = fmaf(wx, v111 - v110, v110);
        float c0  = fmaf(wy, c01 - c00, c00);
        float c1  = fmaf(wy, c11 - c10, c10);
        acc = fmaf(wz, c1 - c0, c0);
    } else {
        // ---- fallback: direct gather (block-uniform branch) ----
        int x1 = x0 + 1, y1 = y0 + 1, z1 = z0 + 1;
        bool all_in  = (x0 >= 0) & (x1 < Wv) & (y0 >= 0) & (y1 < Hv) & (z0 >= 0) & (z1 < Dv);
        bool all_out = (x1 < 0) | (x0 >= Wv) | (y1 < 0) | (y0 >= Hv) | (z1 < 0) | (z0 >= Dv);
        if (all_in) {
            const float* p = sb + ((z0*Hv + y0)*Wv + x0);
            const float* q = p + Hv*Wv;
            float v000 = p[0],    v001 = p[1];
            float v010 = p[Wv],   v011 = p[Wv+1];
            float v100 = q[0],    v101 = q[1];
            float v110 = q[Wv],   v111 = q[Wv+1];
            float c00 = fmaf(wx, v001 - v000, v000);
            float c01 = fmaf(wx, v011 - v010, v010);
            float c10 = fmaf(wx, v101 - v100, v100);
            float c11 = fmaf(wx, v111 - v110, v110);
            float c0  = fmaf(wy, c01 - c00, c00);
            float c1  = fmaf(wy, c11 - c10, c10);
            acc = fmaf(wz, c1 - c0, c0);
        } else if (!all_out) {
            auto gather = [&](int zz, int yy, int xx) -> float {
                bool valid = (xx >= 0) & (xx < Wv) & (yy >= 0) & (yy < Hv) & (zz >= 0) & (zz < Dv);
                int xi = min(max(xx, 0), Wv-1);
                int yi = min(max(yy, 0), Hv-1);
                int zi = min(max(zz, 0), Dv-1);
                float val = sb[(zi*Hv + yi)*Wv + xi];
                return valid ? val : 0.0f;
            };
            float owx = 1.0f - wx, owy = 1.0f - wy, owz = 1.0f - wz;
            acc  = gather(z0, y0, x0) * (owz*owy*owx);
            acc += gather(z0, y0, x1) * (owz*owy*wx);
            acc += gather(z0, y1, x0) * (owz*wy*owx);
            acc += gather(z0, y1, x1) * (owz*wy*wx);
            acc += gather(z1, y0, x0) * (wz*owy*owx);
            acc += gather(z1, y0, x1) * (wz*owy*wx);
            acc += gather(z1, y1, x0) * (wz*wy*owx);
            acc += gather(z1, y1, x1) * (wz*wy*wx);
        }
    }

    __builtin_nontemporal_store(acc, &out[((size_t)(b*Dv + z)*Hv + h)*Wv + w]);
}

extern "C" void kernel_launch(void* const* d_in, const int* in_sizes, int n_in,
                              void* d_out, int out_size, void* d_ws, size_t ws_size,
                              hipStream_t stream) {
    const float* src       = (const float*)d_in[0];
    const float* affine    = (const float*)d_in[1];
    const float* scale     = (const float*)d_in[2];
    const float* translate = (const float*)d_in[3];
    const float* shear     = (const float*)d_in[4];

    float* out  = (float*)d_out;
    float* mats = out + NOUT;   // mat (24 floats) then inv_mat (24 floats)

    compose_mats_kernel<<<1, 64, 0, stream>>>(affine, scale, translate, shear, mats);

    dim3 grid(Wv/TX, Hv/TY, (Dv/TZ)*Bv);
    warp_kernel<<<grid, 512, 0, stream>>>(src, mats, out);
}

// Round 5
// 58.543 us; speedup vs baseline: 1.7914x; 1.7914x over previous
//
#include <hip/hip_runtime.h>
#include <math.h>

#define Bv 2
#define Dv 192
#define Hv 192
#define Wv 192
#define Nv (Dv*Hv*Wv)          // 7,077,888 voxels per batch
#define NOUT (Bv*Nv)           // 14,155,776 warped elements

// Tile per block-iteration: 16 (x) * 8 (y) * 4 (z) = 512 voxels, one per thread.
// Wave = 16x4 x-y patch (ly 0..3 within wave, lz uniform per wave).
#define TSX 16
#define TSY 8
#define TSZ 4
#define NTX (Wv/TSX)           // 12
#define NTY (Hv/TSY)           // 24
#define NTZ (Dv/TSZ)           // 48
#define TILES_PER_B (NTX*NTY*NTZ)   // 13824
#define PBLOCKS 1024           // 4 blocks/CU * 256 CU -> 32 waves/CU resident

__device__ __forceinline__ void mm3(const float a[3][3], const float b[3][3], float c[3][3]) {
#pragma unroll
    for (int i = 0; i < 3; ++i)
#pragma unroll
        for (int j = 0; j < 3; ++j)
            c[i][j] = a[i][0]*b[0][j] + a[i][1]*b[1][j] + a[i][2]*b[2][j];
}

__global__ void compose_mats_kernel(const float* __restrict__ affine,
                                    const float* __restrict__ scale,
                                    const float* __restrict__ translate,
                                    const float* __restrict__ shear,
                                    float* __restrict__ mats_out) {
    int b = threadIdx.x;
    if (b >= Bv) return;

    float ax = affine[b*3+0], ay = affine[b*3+1], az = affine[b*3+2];
    float cx = cosf(ax), sx = sinf(ax);
    float cy = cosf(ay), sy = sinf(ay);
    float cz = cosf(az), sz = sinf(az);

    // _mk_mat transposes the written rows -> these are the transposed matrices.
    float rx[3][3] = {{1.f,0.f,0.f},{0.f,cx,sx},{0.f,-sx,cx}};
    float ry[3][3] = {{cy,0.f,-sy},{0.f,1.f,0.f},{sy,0.f,cy}};
    float rz[3][3] = {{cz,sz,0.f},{-sz,cz,0.f},{0.f,0.f,1.f}};

    float t0 = tanf(shear[b*6+0]), t1 = tanf(shear[b*6+1]), t2 = tanf(shear[b*6+2]);
    float t3 = tanf(shear[b*6+3]), t4 = tanf(shear[b*6+4]), t5 = tanf(shear[b*6+5]);
    float sh[3][3] = {{1.f,t2,t4},{t0,1.f,t5},{t1,t3,1.f}};

    float s0 = scale[b*3+0], s1 = scale[b*3+1], s2 = scale[b*3+2];

    float m1[3][3], m2[3][3], m3s[3][3], mat3[3][3];
    mm3(ry, rx, m1);
    mm3(rz, m1, m2);
#pragma unroll
    for (int j = 0; j < 3; ++j) { m3s[0][j] = s0*m2[0][j]; m3s[1][j] = s1*m2[1][j]; m3s[2][j] = s2*m2[2][j]; }
    mm3(sh, m3s, mat3);

    float tr0 = translate[b*3+0], tr1 = translate[b*3+1], tr2 = translate[b*3+2];

    float a00 = mat3[0][0], a01 = mat3[0][1], a02 = mat3[0][2];
    float a10 = mat3[1][0], a11 = mat3[1][1], a12 = mat3[1][2];
    float a20 = mat3[2][0], a21 = mat3[2][1], a22 = mat3[2][2];
    float c00 =  (a11*a22 - a12*a21);
    float c01 = -(a10*a22 - a12*a20);
    float c02 =  (a10*a21 - a11*a20);
    float det = a00*c00 + a01*c01 + a02*c02;
    float rdet = 1.0f / det;
    float inv3[3][3];
    inv3[0][0] = c00*rdet;
    inv3[0][1] = (a02*a21 - a01*a22)*rdet;
    inv3[0][2] = (a01*a12 - a02*a11)*rdet;
    inv3[1][0] = c01*rdet;
    inv3[1][1] = (a00*a22 - a02*a20)*rdet;
    inv3[1][2] = (a02*a10 - a00*a12)*rdet;
    inv3[2][0] = c02*rdet;
    inv3[2][1] = (a01*a20 - a00*a21)*rdet;
    inv3[2][2] = (a00*a11 - a01*a10)*rdet;

    float* mo = mats_out + b*12;
#pragma unroll
    for (int i = 0; i < 3; ++i) {
        mo[i*4+0] = mat3[i][0]; mo[i*4+1] = mat3[i][1]; mo[i*4+2] = mat3[i][2];
    }
    mo[0*4+3] = tr0; mo[1*4+3] = tr1; mo[2*4+3] = tr2;

    float* io = mats_out + 24 + b*12;
#pragma unroll
    for (int i = 0; i < 3; ++i) {
        io[i*4+0] = inv3[i][0]; io[i*4+1] = inv3[i][1]; io[i*4+2] = inv3[i][2];
        io[i*4+3] = -(inv3[i][0]*tr0 + inv3[i][1]*tr1 + inv3[i][2]*tr2);
    }
}

// 8-byte load from a 4-byte-aligned address (single global_load_dwordx2).
__device__ __forceinline__ float2 ld2(const float* p) {
    float2 r;
    __builtin_memcpy(&r, p, 8);
    return r;
}

__global__ __launch_bounds__(512) void warp_kernel(const float* __restrict__ src,
                                                   const float* __restrict__ mats,
                                                   float* __restrict__ out) {
    int t  = threadIdx.x;
    int lx = t & (TSX-1);          // 0..15
    int ly = (t >> 4) & (TSY-1);   // 0..7  (wave = 16x4 patch: ly&3 within wave)
    int lz = t >> 7;               // 0..3

    float flx_ = lx + 0.5f, fly_ = ly + 0.5f, flz_ = lz + 0.5f;

#pragma unroll 1
    for (int b = 0; b < Bv; ++b) {
        const float* M = mats + b*12;      // uniform -> scalar loads
        float m00 = M[0], m01 = M[1],  m02 = M[2],  m03 = M[3];
        float m10 = M[4], m11 = M[5],  m12 = M[6],  m13 = M[7];
        float m20 = M[8], m21 = M[9],  m22 = M[10], m23 = M[11];

        // ix = m00*(w+.5) + m01*(h+.5) + m02*(z+.5) + Cx
        float Cx = 96.0f*(m03 - m00 - m01 - m02) + 95.5f;
        float Cy = 96.0f*(m13 - m10 - m11 - m12) + 95.5f;
        float Cz = 96.0f*(m23 - m20 - m21 - m22) + 95.5f;

        const float* sb = src + (size_t)b * Nv;
        float* ob = out + (size_t)b * Nv;

#pragma unroll 1
        for (int tile = blockIdx.x; tile < TILES_PER_B; tile += PBLOCKS) {
            int tz = tile / (NTX*NTY);             // /288, compile-time
            int r  = tile - tz*(NTX*NTY);
            int ty = r / NTX;                      // /12, compile-time
            int tx = r - ty*NTX;

            int w = tx*TSX + lx;
            int h = ty*TSY + ly;
            int z = tz*TSZ + lz;

            float fw = tx*TSX + flx_;
            float fh = ty*TSY + fly_;
            float fzc = tz*TSZ + flz_;

            float ix = fmaf(m00, fw, fmaf(m01, fh, fmaf(m02, fzc, Cx)));
            float iy = fmaf(m10, fw, fmaf(m11, fh, fmaf(m12, fzc, Cy)));
            float iz = fmaf(m20, fw, fmaf(m21, fh, fmaf(m22, fzc, Cz)));

            float flx = floorf(ix), fly = floorf(iy), flz = floorf(iz);
            float wx = ix - flx, wy = iy - fly, wz = iz - flz;
            int x0 = (int)flx, y0 = (int)fly, z0 = (int)flz;

            float acc = 0.0f;

            // interior: x0 in [0,190] etc  <=>  (unsigned)x0 < 191
            bool all_in = ((unsigned)x0 < (unsigned)(Wv-1)) &
                          ((unsigned)y0 < (unsigned)(Hv-1)) &
                          ((unsigned)z0 < (unsigned)(Dv-1));

            if (all_in) {
                const float* p = sb + ((z0*Hv + y0)*Wv + x0);
                const float* q = p + Hv*Wv;
                float2 v00 = ld2(p);
                float2 v01 = ld2(p + Wv);
                float2 v10 = ld2(q);
                float2 v11 = ld2(q + Wv);
                float c00 = fmaf(wx, v00.y - v00.x, v00.x);
                float c01 = fmaf(wx, v01.y - v01.x, v01.x);
                float c10 = fmaf(wx, v10.y - v10.x, v10.x);
                float c11 = fmaf(wx, v11.y - v11.x, v11.x);
                float c0  = fmaf(wy, c01 - c00, c00);
                float c1  = fmaf(wy, c11 - c10, c10);
                acc = fmaf(wz, c1 - c0, c0);
            } else {
                int x1 = x0 + 1, y1 = y0 + 1, z1 = z0 + 1;
                bool all_out = (x1 < 0) | (x0 >= Wv) | (y1 < 0) | (y0 >= Hv) | (z1 < 0) | (z0 >= Dv);
                if (!all_out) {
                    auto gather = [&](int zz, int yy, int xx) -> float {
                        bool valid = ((unsigned)xx < (unsigned)Wv) &
                                     ((unsigned)yy < (unsigned)Hv) &
                                     ((unsigned)zz < (unsigned)Dv);
                        int xi = min(max(xx, 0), Wv-1);
                        int yi = min(max(yy, 0), Hv-1);
                        int zi = min(max(zz, 0), Dv-1);
                        float val = sb[(zi*Hv + yi)*Wv + xi];
                        return valid ? val : 0.0f;
                    };
                    float owx = 1.0f - wx, owy = 1.0f - wy, owz = 1.0f - wz;
                    acc  = gather(z0, y0, x0) * (owz*owy*owx);
                    acc += gather(z0, y0, x1) * (owz*owy*wx);
                    acc += gather(z0, y1, x0) * (owz*wy*owx);
                    acc += gather(z0, y1, x1) * (owz*wy*wx);
                    acc += gather(z1, y0, x0) * (wz*owy*owx);
                    acc += gather(z1, y0, x1) * (wz*owy*wx);
                    acc += gather(z1, y1, x0) * (wz*wy*owx);
                    acc += gather(z1, y1, x1) * (wz*wy*wx);
                }
            }

            __builtin_nontemporal_store(acc, &ob[((size_t)z*Hv + h)*Wv + w]);
        }
    }
}

extern "C" void kernel_launch(void* const* d_in, const int* in_sizes, int n_in,
                              void* d_out, int out_size, void* d_ws, size_t ws_size,
                              hipStream_t stream) {
    const float* src       = (const float*)d_in[0];
    const float* affine    = (const float*)d_in[1];
    const float* scale     = (const float*)d_in[2];
    const float* translate = (const float*)d_in[3];
    const float* shear     = (const float*)d_in[4];

    float* out  = (float*)d_out;
    float* mats = out + NOUT;   // mat (24 floats) then inv_mat (24 floats)

    compose_mats_kernel<<<1, 64, 0, stream>>>(affine, scale, translate, shear, mats);

    warp_kernel<<<PBLOCKS, 512, 0, stream>>>(src, mats, out);
}